// Round 1
// baseline (795.463 us; speedup 1.0000x reference)
//
#include <hip/hip_runtime.h>
#include <hip/hip_bf16.h>

// SiglipSdpaAttention: B=32, N=1024, D=1152, R=4, M=N/R=256.
// Pipeline (all GEMMs bf16 MFMA 16x16x32, fp32 accumulate):
//  1. cvt weights + x to bf16; x_m = window-mean(x) (merge commutes with W proj)
//  2. Q = x@Wq^T+bq ; K_m = x_m@Wk^T+bk ; V_m = x_m@Wv^T+bv
//  3. Sc = Q@K_m^T * 1/sqrt(D)  (log(4) bias dropped: softmax-invariant)
//  4. P = softmax(Sc) ; attn = P@V_m (via V_m transposed to [d][m])
//  5. out = attn@Wo^T + bo (fp32)

typedef __bf16 bf16;
typedef __attribute__((ext_vector_type(8))) __bf16 bf16x8;
typedef __attribute__((ext_vector_type(4))) __bf16 bf16x4;
typedef __attribute__((ext_vector_type(4))) float f32x4;

#define GAS __attribute__((address_space(1)))
#define LAS __attribute__((address_space(3)))

__device__ __forceinline__ void async_copy16(const void* g, void* s) {
    __builtin_amdgcn_global_load_lds((GAS unsigned int*)g, (LAS unsigned int*)s, 16, 0, 0);
}

// C = A * B^T (+bias) * scale.  A:[M x K] bf16 row-major, B:[N x K] bf16 row-major,
// C:[M x N] OutT. Tile 128x128, BK=32, 256 threads = 4 waves, each wave 64x64.
// All dims divide tiles exactly (M%128==0, N%128==0, K%32==0).
template <typename OutT, bool HAS_BIAS>
__global__ __launch_bounds__(256) void gemm_bt(
    const bf16* __restrict__ A, const bf16* __restrict__ B,
    const float* __restrict__ bias, OutT* __restrict__ C,
    int N, int K, float scale, long sAb, long sBb, long sCb) {
    __shared__ __align__(16) bf16 As[128 * 32];
    __shared__ __align__(16) bf16 Bs[128 * 32];
    const int tid  = threadIdx.x;
    const int wave = tid >> 6;
    const int lane = tid & 63;
    const int quad = lane >> 4;
    const int l16  = lane & 15;
    const int wM   = (wave >> 1) * 64;
    const int wN   = (wave & 1) * 64;

    const long zb = blockIdx.z;
    A += zb * sAb;
    B += zb * sBb;
    C += zb * sCb;

    const int rowBase = blockIdx.y * 128;
    const int colBase = blockIdx.x * 128;

    // staging granules: 512 x 16B per tile; each thread 2 per tile.
    const int g0 = wave * 64 + lane;   // 0..255
    const int r0 = g0 >> 2;            // row 0..63
    const int c0 = (g0 & 3) * 8;       // bf16 col offset within BK=32
    const bf16* a0 = A + (long)(rowBase + r0) * K + c0;
    const bf16* a1 = A + (long)(rowBase + 64 + r0) * K + c0;
    const bf16* b0 = B + (long)(colBase + r0) * K + c0;
    const bf16* b1 = B + (long)(colBase + 64 + r0) * K + c0;
    // LDS dest: wave-uniform base + lane*16 (HW rule for global_load_lds)
    char* lA0 = (char*)As + wave * 1024;
    char* lA1 = (char*)As + 4096 + wave * 1024;
    char* lB0 = (char*)Bs + wave * 1024;
    char* lB1 = (char*)Bs + 4096 + wave * 1024;

    f32x4 acc[4][4] = {};

    const int kt = K >> 5;
    for (int k = 0; k < kt; ++k) {
        __syncthreads();
        async_copy16(a0, lA0);
        async_copy16(a1, lA1);
        async_copy16(b0, lB0);
        async_copy16(b1, lB1);
        a0 += 32; a1 += 32; b0 += 32; b1 += 32;
        __syncthreads();
        bf16x8 af[4], bfv[4];
#pragma unroll
        for (int t = 0; t < 4; ++t) {
            af[t]  = *(const bf16x8*)(As + (wM + t * 16 + l16) * 32 + quad * 8);
            bfv[t] = *(const bf16x8*)(Bs + (wN + t * 16 + l16) * 32 + quad * 8);
        }
#pragma unroll
        for (int mt = 0; mt < 4; ++mt)
#pragma unroll
            for (int nt = 0; nt < 4; ++nt)
                acc[mt][nt] = __builtin_amdgcn_mfma_f32_16x16x32_bf16(
                    af[mt], bfv[nt], acc[mt][nt], 0, 0, 0);
    }

    // C/D layout: col = lane&15, row = quad*4 + reg  [measured m89/m91]
#pragma unroll
    for (int mt = 0; mt < 4; ++mt) {
        const int row = rowBase + wM + mt * 16 + quad * 4;
#pragma unroll
        for (int nt = 0; nt < 4; ++nt) {
            const int col = colBase + wN + nt * 16 + l16;
            const float bv = HAS_BIAS ? bias[col] : 0.0f;
#pragma unroll
            for (int r = 0; r < 4; ++r) {
                float v = acc[mt][nt][r] * scale + bv;
                C[(long)(row + r) * N + col] = (OutT)v;
            }
        }
    }
}

__global__ void cvt_bf16_k(const float* __restrict__ src, bf16* __restrict__ dst, int n4) {
    int i = blockIdx.x * 256 + threadIdx.x;
    if (i >= n4) return;
    float4 v = ((const float4*)src)[i];
    bf16x4 o = {(bf16)v.x, (bf16)v.y, (bf16)v.z, (bf16)v.w};
    ((bf16x4*)dst)[i] = o;
}

// x:[8192*4 x 1152] f32 -> xm:[8192 x 1152] bf16 (mean over 4 consecutive rows)
__global__ void merge_x_k(const float* __restrict__ x, bf16* __restrict__ xm) {
    int i = blockIdx.x * 256 + threadIdx.x;  // 8192*288 exact
    int row = i / 288;
    int c4 = i - row * 288;
    const float4* p = (const float4*)(x + (long)row * 4608) + c4;
    float4 a = p[0], b = p[288], c = p[576], d = p[864];
    float4 s;
    s.x = (a.x + b.x + c.x + d.x) * 0.25f;
    s.y = (a.y + b.y + c.y + d.y) * 0.25f;
    s.z = (a.z + b.z + c.z + d.z) * 0.25f;
    s.w = (a.w + b.w + c.w + d.w) * 0.25f;
    bf16x4 o = {(bf16)s.x, (bf16)s.y, (bf16)s.z, (bf16)s.w};
    *(bf16x4*)(xm + (long)row * 1152 + c4 * 4) = o;
}

// V:[b*256+m][1152] -> VT:[b][1152][256]
__global__ void transpose_vm_k(const bf16* __restrict__ V, bf16* __restrict__ VT) {
    __shared__ bf16 t[64][65];
    const int tid = threadIdx.x;
    const int b = blockIdx.z;
    const int d0 = blockIdx.x * 64, m0 = blockIdx.y * 64;
#pragma unroll
    for (int p = 0; p < 2; ++p) {
        int r = (tid >> 3) + p * 32;
        int c = (tid & 7) * 8;
        bf16x8 v = *(const bf16x8*)(V + (long)(b * 256 + m0 + r) * 1152 + d0 + c);
#pragma unroll
        for (int j = 0; j < 8; ++j) t[c + j][r] = v[j];
    }
    __syncthreads();
#pragma unroll
    for (int p = 0; p < 2; ++p) {
        int r = (tid >> 3) + p * 32;
        int c = (tid & 7) * 8;
        bf16x8 o;
#pragma unroll
        for (int j = 0; j < 8; ++j) o[j] = t[r][c + j];
        *(bf16x8*)(VT + (long)b * 294912 + (long)(d0 + r) * 256 + m0 + c) = o;
    }
}

// rows of 256 fp32 -> softmax -> bf16. One wave per row.
__global__ void softmax_k(const float* __restrict__ S, bf16* __restrict__ P) {
    const int row = blockIdx.x * 4 + (threadIdx.x >> 6);
    const int lane = threadIdx.x & 63;
    const float4 v = ((const float4*)(S + (long)row * 256))[lane];
    float m = fmaxf(fmaxf(v.x, v.y), fmaxf(v.z, v.w));
#pragma unroll
    for (int off = 32; off > 0; off >>= 1) m = fmaxf(m, __shfl_xor(m, off, 64));
    float e0 = __expf(v.x - m), e1 = __expf(v.y - m);
    float e2 = __expf(v.z - m), e3 = __expf(v.w - m);
    float s = e0 + e1 + e2 + e3;
#pragma unroll
    for (int off = 32; off > 0; off >>= 1) s += __shfl_xor(s, off, 64);
    const float inv = 1.0f / s;
    bf16x4 o = {(bf16)(e0 * inv), (bf16)(e1 * inv), (bf16)(e2 * inv), (bf16)(e3 * inv)};
    *(bf16x4*)(P + (long)row * 256 + lane * 4) = o;
}

extern "C" void kernel_launch(void* const* d_in, const int* in_sizes, int n_in,
                              void* d_out, int out_size, void* d_ws, size_t ws_size,
                              hipStream_t stream) {
    const float* x  = (const float*)d_in[0];
    const float* Wq = (const float*)d_in[1];
    const float* bq = (const float*)d_in[2];
    const float* Wk = (const float*)d_in[3];
    const float* bk = (const float*)d_in[4];
    const float* Wv = (const float*)d_in[5];
    const float* bv = (const float*)d_in[6];
    const float* Wo = (const float*)d_in[7];
    const float* bo = (const float*)d_in[8];
    float* out = (float*)d_out;
    char* ws = (char*)d_ws;

    // ws layout (142,737,408 B total)
    bf16* Wq_b = (bf16*)(ws);
    bf16* Wk_b = (bf16*)(ws + 2654208);
    bf16* Wv_b = (bf16*)(ws + 5308416);
    bf16* Wo_b = (bf16*)(ws + 7962624);
    bf16* xm_b = (bf16*)(ws + 10616832);    // 18.9MB; reused as P after K/V GEMMs
    bf16* Q_b  = (bf16*)(ws + 29491200);    // 75.5MB; reused as attn after scores
    bf16* Km_b = (bf16*)(ws + 104988672);   // 18.9MB
    bf16* VmT  = (bf16*)(ws + 123863040);   // 18.9MB
    bf16* P_b  = xm_b;
    bf16* attn = Q_b;

    // d_out (151MB) as scratch; all dead before final GEMM writes it.
    bf16* x_b = (bf16*)d_out;                          // 75.5MB
    float* Sc = (float*)d_out + 18874368;              // 33.5MB @ byte 75.5M
    bf16* Vm  = (bf16*)((char*)d_out + 109051904);     // 18.9MB

    // 1. dtype prep
    cvt_bf16_k<<<1296, 256, 0, stream>>>(Wq, Wq_b, 331776);
    cvt_bf16_k<<<1296, 256, 0, stream>>>(Wk, Wk_b, 331776);
    cvt_bf16_k<<<1296, 256, 0, stream>>>(Wv, Wv_b, 331776);
    cvt_bf16_k<<<1296, 256, 0, stream>>>(Wo, Wo_b, 331776);
    cvt_bf16_k<<<36864, 256, 0, stream>>>(x, x_b, 9437184);
    merge_x_k<<<9216, 256, 0, stream>>>(x, xm_b);

    // 2. projections
    gemm_bt<bf16, true><<<dim3(9, 256, 1), 256, 0, stream>>>(
        x_b, Wq_b, bq, Q_b, 1152, 1152, 1.0f, 0, 0, 0);
    gemm_bt<bf16, true><<<dim3(9, 64, 1), 256, 0, stream>>>(
        xm_b, Wk_b, bk, Km_b, 1152, 1152, 1.0f, 0, 0, 0);
    gemm_bt<bf16, true><<<dim3(9, 64, 1), 256, 0, stream>>>(
        xm_b, Wv_b, bv, Vm, 1152, 1152, 1.0f, 0, 0, 0);
    transpose_vm_k<<<dim3(18, 4, 32), 256, 0, stream>>>(Vm, VmT);

    // 3. scores = Q @ Km^T * 1/sqrt(1152)   (batched over 32)
    gemm_bt<float, false><<<dim3(2, 8, 32), 256, 0, stream>>>(
        Q_b, Km_b, nullptr, Sc, 256, 1152, 0.029462782549439484f,
        1024L * 1152, 256L * 1152, 1024L * 256);

    // 4. softmax + PV
    softmax_k<<<8192, 256, 0, stream>>>(Sc, P_b);
    gemm_bt<bf16, false><<<dim3(9, 8, 32), 256, 0, stream>>>(
        P_b, VmT, nullptr, attn, 1152, 256, 1.0f,
        1024L * 256, 1152L * 256, 1024L * 1152);

    // 5. out = attn @ Wo^T + bo (fp32)
    gemm_bt<float, true><<<dim3(9, 256, 1), 256, 0, stream>>>(
        attn, Wo_b, bo, out, 1152, 1152, 1.0f, 0, 0, 0);
}

// Round 2
// 688.759 us; speedup vs baseline: 1.1549x; 1.1549x over previous
//
#include <hip/hip_runtime.h>
#include <hip/hip_bf16.h>

// SiglipSdpaAttention: B=32, N=1024, D=1152, R=4, M=N/R=256.
//  1. cvt weights to bf16 (Wk,Wv contiguous -> one KV GEMM); cvt x + window-mean in one pass
//  2. Q = x@Wq^T+bq ; [K_m|V_m] = x_m@[Wk;Wv]^T+[bk;bv]   (merge commutes with proj)
//  3. P = softmax(Q@K_m^T / sqrt(D)) fused in one kernel (log(4) bias is softmax-invariant)
//  4. attn = P@V_m (via V_m^T) ; out = attn@Wo^T + bo
// All GEMMs: bf16 MFMA 16x16x32, 128x128 tile, global_load_lds width-16 staging,
// XCD-aware swizzle: all x-tiles of an A-panel on one XCD (A fetched once per panel).

typedef __bf16 bf16;
typedef __attribute__((ext_vector_type(8))) __bf16 bf16x8;
typedef __attribute__((ext_vector_type(4))) __bf16 bf16x4;
typedef __attribute__((ext_vector_type(4))) float f32x4;

#define GAS __attribute__((address_space(1)))
#define LAS __attribute__((address_space(3)))

__device__ __forceinline__ void async_copy16(const void* g, void* s) {
    __builtin_amdgcn_global_load_lds((GAS unsigned int*)g, (LAS unsigned int*)s, 16, 0, 0);
}

// C = A * B^T (+bias) * scale. A:[M x K] rowmajor (lda), B:[N x K] rowmajor (ldb),
// C:[M x N] (ldc). Tile 128x128, BK=32, 256 thr = 4 waves (2x2 of 64x64).
template <typename OutT, bool HAS_BIAS>
__global__ __launch_bounds__(256) void gemm_bt(
    const bf16* __restrict__ A, const bf16* __restrict__ B,
    const float* __restrict__ bias, OutT* __restrict__ C,
    int N, int K, int lda, int ldb, int ldc, float scale,
    long sAb, long sBb, long sCb) {
    __shared__ __align__(16) bf16 As[128 * 32];
    __shared__ __align__(16) bf16 Bs[128 * 32];
    const int tid  = threadIdx.x;
    const int wave = tid >> 6;
    const int lane = tid & 63;
    const int quad = lane >> 4;
    const int l16  = lane & 15;
    const int wM   = (wave >> 1) * 64;
    const int wN   = (wave & 1) * 64;

    // XCD swizzle: dispatch id lid -> XCD lid%8 (round-robin). Remap so that all
    // x-tiles of panel vy sit on one XCD, sweeping x (group width 9) before next panel.
    int bx = blockIdx.x, by = blockIdx.y;
    const int nbx = gridDim.x, nby = gridDim.y;
    if (((nby & 7) == 0) && (nbx % 9 == 0)) {
        int lid = by * nbx + bx;
        int xcd = lid & 7;
        int s   = lid >> 3;
        int Pn  = nby >> 3;         // panels per XCD
        int gsz = 9 * Pn;           // blocks per column-group per XCD
        int g   = s / gsz;
        int rem = s - g * gsz;
        int p   = rem / 9;
        by = p * 8 + xcd;
        bx = g * 9 + (rem - p * 9);
    }

    const long zb = blockIdx.z;
    A += zb * sAb;
    B += zb * sBb;
    C += zb * sCb;

    const int rowBase = by * 128;
    const int colBase = bx * 128;

    const int g0 = wave * 64 + lane;   // 0..255 staging granule
    const int r0 = g0 >> 2;            // row 0..63
    const int c0 = (g0 & 3) * 8;       // bf16 col offset within BK=32
    const bf16* a0 = A + (long)(rowBase + r0) * lda + c0;
    const bf16* a1 = A + (long)(rowBase + 64 + r0) * lda + c0;
    const bf16* b0 = B + (long)(colBase + r0) * ldb + c0;
    const bf16* b1 = B + (long)(colBase + 64 + r0) * ldb + c0;
    char* lA0 = (char*)As + wave * 1024;
    char* lA1 = (char*)As + 4096 + wave * 1024;
    char* lB0 = (char*)Bs + wave * 1024;
    char* lB1 = (char*)Bs + 4096 + wave * 1024;

    f32x4 acc[4][4] = {};

    const int kt = K >> 5;
    for (int k = 0; k < kt; ++k) {
        __syncthreads();
        async_copy16(a0, lA0);
        async_copy16(a1, lA1);
        async_copy16(b0, lB0);
        async_copy16(b1, lB1);
        a0 += 32; a1 += 32; b0 += 32; b1 += 32;
        __syncthreads();
        bf16x8 af[4], bfv[4];
#pragma unroll
        for (int t = 0; t < 4; ++t) {
            af[t]  = *(const bf16x8*)(As + (wM + t * 16 + l16) * 32 + quad * 8);
            bfv[t] = *(const bf16x8*)(Bs + (wN + t * 16 + l16) * 32 + quad * 8);
        }
#pragma unroll
        for (int mt = 0; mt < 4; ++mt)
#pragma unroll
            for (int nt = 0; nt < 4; ++nt)
                acc[mt][nt] = __builtin_amdgcn_mfma_f32_16x16x32_bf16(
                    af[mt], bfv[nt], acc[mt][nt], 0, 0, 0);
    }

    // C/D layout: col = lane&15, row = quad*4 + reg  [m89/m91]
#pragma unroll
    for (int mt = 0; mt < 4; ++mt) {
        const int row = rowBase + wM + mt * 16 + quad * 4;
#pragma unroll
        for (int nt = 0; nt < 4; ++nt) {
            const int col = colBase + wN + nt * 16 + l16;
            const float bv = HAS_BIAS ? bias[col] : 0.0f;
#pragma unroll
            for (int r = 0; r < 4; ++r) {
                float v = acc[mt][nt][r] * scale + bv;
                C[(long)(row + r) * ldc + col] = (OutT)v;
            }
        }
    }
}

// Fused scores+softmax: per block 128 Q-rows x all 256 cols of one batch.
// S = Q@Km^T; P = softmax(S*scale). 512 thr = 8 waves (2x4 of 64x64).
__global__ __launch_bounds__(512) void scores_softmax_k(
    const bf16* __restrict__ Q, const bf16* __restrict__ KV,
    bf16* __restrict__ P) {
    __shared__ __align__(16) bf16 As[128 * 32];
    __shared__ __align__(16) bf16 Bs[256 * 32];
    __shared__ float red[128][4];
    __shared__ float red2[128][4];
    const int tid  = threadIdx.x;
    const int wave = tid >> 6;   // 0..7
    const int lane = tid & 63;
    const int quad = lane >> 4;
    const int l16  = lane & 15;
    const int wM   = (wave >> 2) * 64;
    const int wN   = (wave & 3) * 64;
    const int wc   = wave & 3;

    // grid (8 row-tiles, 32 batches); swizzle: all 8 tiles of a batch on one XCD.
    int bx = blockIdx.x, by = blockIdx.y;
    {
        int lid = by * 8 + bx;
        int xcd = lid & 7;
        int s   = lid >> 3;       // 0..31
        by = (s >> 3) * 8 + xcd;  // batch
        bx = s & 7;               // row tile
    }
    const long b = by;
    const bf16* A = Q + (b * 1024 + (long)bx * 128) * 1152;
    const bf16* B = KV + b * 256 * 2304;   // Km rows, stride 2304

    const int ra = tid >> 2, ca = (tid & 3) * 8;
    const bf16* a0 = A + (long)ra * 1152 + ca;
    const bf16* b0 = B + (long)ra * 2304 + ca;          // rows 0..127
    const bf16* b1 = B + (long)(128 + ra) * 2304 + ca;  // rows 128..255
    char* lA  = (char*)As + wave * 1024;
    char* lB0 = (char*)Bs + wave * 1024;
    char* lB1 = (char*)Bs + 8192 + wave * 1024;

    f32x4 acc[4][4] = {};
#pragma unroll 1
    for (int k = 0; k < 36; ++k) {
        __syncthreads();
        async_copy16(a0, lA);
        async_copy16(b0, lB0);
        async_copy16(b1, lB1);
        a0 += 32; b0 += 32; b1 += 32;
        __syncthreads();
        bf16x8 af[4], bfv[4];
#pragma unroll
        for (int t = 0; t < 4; ++t) {
            af[t]  = *(const bf16x8*)(As + (wM + t * 16 + l16) * 32 + quad * 8);
            bfv[t] = *(const bf16x8*)(Bs + (wN + t * 16 + l16) * 32 + quad * 8);
        }
#pragma unroll
        for (int mt = 0; mt < 4; ++mt)
#pragma unroll
            for (int nt = 0; nt < 4; ++nt)
                acc[mt][nt] = __builtin_amdgcn_mfma_f32_16x16x32_bf16(
                    af[mt], bfv[nt], acc[mt][nt], 0, 0, 0);
    }

    const float scale = 0.029462782549439484f;  // 1/sqrt(1152)

    // phase 1: per-row max over this wave's 64 cols -> red[row][wc]
#pragma unroll
    for (int mt = 0; mt < 4; ++mt)
#pragma unroll
        for (int r = 0; r < 4; ++r) {
            float pm = fmaxf(fmaxf(acc[mt][0][r], acc[mt][1][r]),
                             fmaxf(acc[mt][2][r], acc[mt][3][r]));
#pragma unroll
            for (int off = 1; off <= 8; off <<= 1) pm = fmaxf(pm, __shfl_xor(pm, off));
            if (l16 == 0) red[wM + mt * 16 + quad * 4 + r][wc] = pm;
        }
    __syncthreads();
    // phase 2: exp + per-wave sum -> red2[row][wc]
#pragma unroll
    for (int mt = 0; mt < 4; ++mt)
#pragma unroll
        for (int r = 0; r < 4; ++r) {
            const int R = wM + mt * 16 + quad * 4 + r;
            float4 q = *(const float4*)red[R];
            float m = fmaxf(fmaxf(q.x, q.y), fmaxf(q.z, q.w));
            float ps = 0.0f;
#pragma unroll
            for (int nt = 0; nt < 4; ++nt) {
                float e = __expf((acc[mt][nt][r] - m) * scale);
                acc[mt][nt][r] = e;
                ps += e;
            }
#pragma unroll
            for (int off = 1; off <= 8; off <<= 1) ps += __shfl_xor(ps, off);
            if (l16 == 0) red2[R][wc] = ps;
        }
    __syncthreads();
    // phase 3: normalize + store bf16
#pragma unroll
    for (int mt = 0; mt < 4; ++mt)
#pragma unroll
        for (int r = 0; r < 4; ++r) {
            const int R = wM + mt * 16 + quad * 4 + r;
            float4 q = *(const float4*)red2[R];
            float inv = 1.0f / (q.x + q.y + q.z + q.w);
            const long gr = b * 1024 + (long)bx * 128 + R;
#pragma unroll
            for (int nt = 0; nt < 4; ++nt)
                P[gr * 256 + wN + nt * 16 + l16] = (bf16)(acc[mt][nt][r] * inv);
        }
}

// 4 weight matrices fp32 -> bf16; dst order: Wq, Wk, Wv, Wo (Wk,Wv contiguous = Wkv).
__global__ void cvt_w_k(const float* __restrict__ Wq, const float* __restrict__ Wk,
                        const float* __restrict__ Wv, const float* __restrict__ Wo,
                        bf16* __restrict__ dst) {
    const float* src = blockIdx.y == 0 ? Wq : blockIdx.y == 1 ? Wk
                     : blockIdx.y == 2 ? Wv : Wo;
    bf16* d = dst + (long)blockIdx.y * 1327104;
    int i = blockIdx.x * 256 + threadIdx.x;  // 331776 float4 per matrix, exact
    float4 v = ((const float4*)src)[i];
    bf16x4 o = {(bf16)v.x, (bf16)v.y, (bf16)v.z, (bf16)v.w};
    ((bf16x4*)d)[i] = o;
}

__global__ void concat_bias_k(const float* __restrict__ bk, const float* __restrict__ bv,
                              float* __restrict__ bkv) {
    int i = blockIdx.x * 256 + threadIdx.x;  // 2304 exact
    bkv[i] = i < 1152 ? bk[i] : bv[i - 1152];
}

// x fp32 [32768 x 1152] -> xb bf16 (all rows) + xm bf16 (mean over 4-row windows)
__global__ void cvt_merge_x_k(const float* __restrict__ x, bf16* __restrict__ xb,
                              bf16* __restrict__ xm) {
    int i = blockIdx.x * 256 + threadIdx.x;  // 8192*288 exact
    int w = i / 288;
    int c4 = i - w * 288;
    const float4* p = (const float4*)(x + (long)w * 4608) + c4;
    float4 a = p[0], b = p[288], c = p[576], d = p[864];
    bf16x4 oa = {(bf16)a.x, (bf16)a.y, (bf16)a.z, (bf16)a.w};
    bf16x4 ob = {(bf16)b.x, (bf16)b.y, (bf16)b.z, (bf16)b.w};
    bf16x4 oc = {(bf16)c.x, (bf16)c.y, (bf16)c.z, (bf16)c.w};
    bf16x4 od = {(bf16)d.x, (bf16)d.y, (bf16)d.z, (bf16)d.w};
    bf16* base = xb + (long)w * 4608 + c4 * 4;
    *(bf16x4*)(base)        = oa;
    *(bf16x4*)(base + 1152) = ob;
    *(bf16x4*)(base + 2304) = oc;
    *(bf16x4*)(base + 3456) = od;
    float4 s;
    s.x = (a.x + b.x + c.x + d.x) * 0.25f;
    s.y = (a.y + b.y + c.y + d.y) * 0.25f;
    s.z = (a.z + b.z + c.z + d.z) * 0.25f;
    s.w = (a.w + b.w + c.w + d.w) * 0.25f;
    bf16x4 o = {(bf16)s.x, (bf16)s.y, (bf16)s.z, (bf16)s.w};
    *(bf16x4*)(xm + (long)w * 1152 + c4 * 4) = o;
}

// V part of KV [b*256+m][2304]@+1152 -> VT:[b][1152][256]
__global__ void transpose_vm_k(const bf16* __restrict__ KV, bf16* __restrict__ VT) {
    __shared__ bf16 t[64][65];
    const int tid = threadIdx.x;
    const int b = blockIdx.z;
    const int d0 = blockIdx.x * 64, m0 = blockIdx.y * 64;
#pragma unroll
    for (int p = 0; p < 2; ++p) {
        int r = (tid >> 3) + p * 32;
        int c = (tid & 7) * 8;
        bf16x8 v = *(const bf16x8*)(KV + (long)(b * 256 + m0 + r) * 2304 + 1152 + d0 + c);
#pragma unroll
        for (int j = 0; j < 8; ++j) t[c + j][r] = v[j];
    }
    __syncthreads();
#pragma unroll
    for (int p = 0; p < 2; ++p) {
        int r = (tid >> 3) + p * 32;
        int c = (tid & 7) * 8;
        bf16x8 o;
#pragma unroll
        for (int j = 0; j < 8; ++j) o[j] = t[r][c + j];
        *(bf16x8*)(VT + (long)b * 294912 + (long)(d0 + r) * 256 + m0 + c) = o;
    }
}

extern "C" void kernel_launch(void* const* d_in, const int* in_sizes, int n_in,
                              void* d_out, int out_size, void* d_ws, size_t ws_size,
                              hipStream_t stream) {
    const float* x  = (const float*)d_in[0];
    const float* Wq = (const float*)d_in[1];
    const float* bq = (const float*)d_in[2];
    const float* Wk = (const float*)d_in[3];
    const float* bk = (const float*)d_in[4];
    const float* Wv = (const float*)d_in[5];
    const float* bv = (const float*)d_in[6];
    const float* Wo = (const float*)d_in[7];
    const float* bo = (const float*)d_in[8];
    float* out = (float*)d_out;
    char* ws = (char*)d_ws;

    // ws layout (105 MB used)
    bf16* W4    = (bf16*)(ws);                 // Wq|Wk|Wv|Wo bf16, 10,616,832 B
    bf16* Wq_b  = W4;
    bf16* Wkv_b = W4 + 1327104;                // Wk;Wv rows 0..2303
    bf16* Wo_b  = W4 + 3981312;
    float* bkv  = (float*)(ws + 10616832);     // 9,216 B
    bf16* xm_b  = (bf16*)(ws + 10626048);      // 18,874,368 B
    bf16* Q_b   = (bf16*)(ws + 29500416);      // 75,497,472 B; reused as attn
    bf16* attn  = Q_b;

    // d_out (151 MB) as scratch; all dead before final GEMM writes it.
    bf16* x_b = (bf16*)d_out;                          // 75,497,472 B
    bf16* KV  = (bf16*)((char*)d_out + 75497472);      // 37,748,736 B (Km | Vm per row)
    bf16* VmT = (bf16*)((char*)d_out + 113246208);     // 18,874,368 B
    bf16* P_b = (bf16*)((char*)d_out + 132120576);     // 16,777,216 B

    // 1. dtype prep
    cvt_w_k<<<dim3(1296, 4), 256, 0, stream>>>(Wq, Wk, Wv, Wo, W4);
    concat_bias_k<<<9, 256, 0, stream>>>(bk, bv, bkv);
    cvt_merge_x_k<<<9216, 256, 0, stream>>>(x, x_b, xm_b);

    // 2. projections: Q [32768x1152]; KV [8192x2304]
    gemm_bt<bf16, true><<<dim3(9, 256, 1), 256, 0, stream>>>(
        x_b, Wq_b, bq, Q_b, 1152, 1152, 1152, 1152, 1152, 1.0f, 0, 0, 0);
    gemm_bt<bf16, true><<<dim3(18, 64, 1), 256, 0, stream>>>(
        xm_b, Wkv_b, bkv, KV, 2304, 1152, 1152, 1152, 2304, 1.0f, 0, 0, 0);
    transpose_vm_k<<<dim3(18, 4, 32), 256, 0, stream>>>(KV, VmT);

    // 3. P = softmax(Q@Km^T / sqrt(D))
    scores_softmax_k<<<dim3(8, 32), 512, 0, stream>>>(Q_b, KV, P_b);

    // 4. attn = P@VmT^T (batched)
    gemm_bt<bf16, false><<<dim3(9, 8, 32), 256, 0, stream>>>(
        P_b, VmT, nullptr, attn, 1152, 256, 256, 256, 1152, 1.0f,
        1024L * 256, 1152L * 256, 1024L * 1152);

    // 5. out = attn @ Wo^T + bo (fp32)
    gemm_bt<float, true><<<dim3(9, 256, 1), 256, 0, stream>>>(
        attn, Wo_b, bo, out, 1152, 1152, 1152, 1152, 1152, 1.0f, 0, 0, 0);
}

// Round 3
// 500.561 us; speedup vs baseline: 1.5891x; 1.3760x over previous
//
#include <hip/hip_runtime.h>
#include <hip/hip_bf16.h>

// SiglipSdpaAttention: B=32, N=1024, D=1152, R=4, M=N/R=256.
// Algebra: merge commutes with projections; softmax drops row-constant terms.
//   S = Q@Km^T: expand -> x·(Wq^T Wk)·x_m^T + c[m],  c = x_m·(Wk^T bq)
//       (bk and bq·bk terms are row-constant -> softmax-invariant -> dropped)
//   out = P·Vm·Wo^T + bo = P·(x_m·(Wo Wv)^T + Wo bv) + bo
// So the two M=32768 D×D GEMMs are replaced by one M=8192 GEMM:
//   [U | VW] = x_m @ [Wqk ; Wvo]^T + [0 | Wo·bv],  Wqk=Wq^T·Wk, Wvo=Wo·Wv
//   P = softmax((x@U^T + c[m]) / sqrt(D));  out = P@VW + bo
// Total ~88 GFLOP (vs 260 naive). All GEMMs bf16 MFMA 16x16x32, 128x128 tile,
// global_load_lds width-16 staging, XCD swizzle for panel locality.

typedef __bf16 bf16;
typedef __attribute__((ext_vector_type(8))) __bf16 bf16x8;
typedef __attribute__((ext_vector_type(4))) __bf16 bf16x4;
typedef __attribute__((ext_vector_type(4))) float f32x4;

#define GAS __attribute__((address_space(1)))
#define LAS __attribute__((address_space(3)))

__device__ __forceinline__ void async_copy16(const void* g, void* s) {
    __builtin_amdgcn_global_load_lds((GAS unsigned int*)g, (LAS unsigned int*)s, 16, 0, 0);
}

// C = A * B^T (+bias) * scale. A:[M x K] rowmajor (lda), B:[N x K] rowmajor (ldb),
// C:[M x N] (ldc). Tile 128x128, BK=32, 256 thr = 4 waves (2x2 of 64x64).
template <typename OutT, bool HAS_BIAS>
__global__ __launch_bounds__(256) void gemm_bt(
    const bf16* __restrict__ A, const bf16* __restrict__ B,
    const float* __restrict__ bias, OutT* __restrict__ C,
    int N, int K, int lda, int ldb, int ldc, float scale,
    long sAb, long sBb, long sCb) {
    __shared__ __align__(16) bf16 As[128 * 32];
    __shared__ __align__(16) bf16 Bs[128 * 32];
    const int tid  = threadIdx.x;
    const int wave = tid >> 6;
    const int lane = tid & 63;
    const int quad = lane >> 4;
    const int l16  = lane & 15;
    const int wM   = (wave >> 1) * 64;
    const int wN   = (wave & 1) * 64;

    // XCD swizzle: all x-tiles of an A-panel on one XCD (A fetched once/panel).
    int bx = blockIdx.x, by = blockIdx.y;
    const int nbx = gridDim.x, nby = gridDim.y;
    if (((nby & 7) == 0) && (nbx % 9 == 0)) {
        int lid = by * nbx + bx;
        int xcd = lid & 7;
        int s   = lid >> 3;
        int Pn  = nby >> 3;
        int gsz = 9 * Pn;
        int g   = s / gsz;
        int rem = s - g * gsz;
        int p   = rem / 9;
        by = p * 8 + xcd;
        bx = g * 9 + (rem - p * 9);
    }

    const long zb = blockIdx.z;
    A += zb * sAb;
    B += zb * sBb;
    C += zb * sCb;

    const int rowBase = by * 128;
    const int colBase = bx * 128;

    const int g0 = wave * 64 + lane;
    const int r0 = g0 >> 2;
    const int c0 = (g0 & 3) * 8;
    const bf16* a0 = A + (long)(rowBase + r0) * lda + c0;
    const bf16* a1 = A + (long)(rowBase + 64 + r0) * lda + c0;
    const bf16* b0 = B + (long)(colBase + r0) * ldb + c0;
    const bf16* b1 = B + (long)(colBase + 64 + r0) * ldb + c0;
    char* lA0 = (char*)As + wave * 1024;
    char* lA1 = (char*)As + 4096 + wave * 1024;
    char* lB0 = (char*)Bs + wave * 1024;
    char* lB1 = (char*)Bs + 4096 + wave * 1024;

    f32x4 acc[4][4] = {};

    const int kt = K >> 5;
    for (int k = 0; k < kt; ++k) {
        __syncthreads();
        async_copy16(a0, lA0);
        async_copy16(a1, lA1);
        async_copy16(b0, lB0);
        async_copy16(b1, lB1);
        a0 += 32; a1 += 32; b0 += 32; b1 += 32;
        __syncthreads();
        bf16x8 af[4], bfv[4];
#pragma unroll
        for (int t = 0; t < 4; ++t) {
            af[t]  = *(const bf16x8*)(As + (wM + t * 16 + l16) * 32 + quad * 8);
            bfv[t] = *(const bf16x8*)(Bs + (wN + t * 16 + l16) * 32 + quad * 8);
        }
#pragma unroll
        for (int mt = 0; mt < 4; ++mt)
#pragma unroll
            for (int nt = 0; nt < 4; ++nt)
                acc[mt][nt] = __builtin_amdgcn_mfma_f32_16x16x32_bf16(
                    af[mt], bfv[nt], acc[mt][nt], 0, 0, 0);
    }

    // C/D layout: col = lane&15, row = quad*4 + reg  [m89/m91]
#pragma unroll
    for (int mt = 0; mt < 4; ++mt) {
        const int row = rowBase + wM + mt * 16 + quad * 4;
#pragma unroll
        for (int nt = 0; nt < 4; ++nt) {
            const int col = colBase + wN + nt * 16 + l16;
            const float bv = HAS_BIAS ? bias[col] : 0.0f;
#pragma unroll
            for (int r = 0; r < 4; ++r) {
                float v = acc[mt][nt][r] * scale + bv;
                C[(long)(row + r) * ldc + col] = (OutT)v;
            }
        }
    }
}

// Fused scores+softmax: S = x@U^T + c[m]; P = softmax(S*scale).
// Per block: 128 rows x 256 cols of one batch. 512 thr = 8 waves (2x4 of 64x64).
__global__ __launch_bounds__(512) void scores_softmax_k(
    const bf16* __restrict__ X, const bf16* __restrict__ UVW,
    const float* __restrict__ cvec, bf16* __restrict__ P) {
    __shared__ __align__(16) bf16 As[128 * 32];
    __shared__ __align__(16) bf16 Bs[256 * 32];
    __shared__ float red[128][4];
    __shared__ float red2[128][4];
    const int tid  = threadIdx.x;
    const int wave = tid >> 6;
    const int lane = tid & 63;
    const int quad = lane >> 4;
    const int l16  = lane & 15;
    const int wM   = (wave >> 2) * 64;
    const int wN   = (wave & 3) * 64;
    const int wc   = wave & 3;

    int bx = blockIdx.x, by = blockIdx.y;
    {
        int lid = by * 8 + bx;
        int xcd = lid & 7;
        int s   = lid >> 3;
        by = (s >> 3) * 8 + xcd;
        bx = s & 7;
    }
    const long b = by;
    const bf16* A = X + (b * 1024 + (long)bx * 128) * 1152;
    const bf16* B = UVW + b * 256 * 2304;   // U part: cols 0..1151, stride 2304

    const int ra = tid >> 2, ca = (tid & 3) * 8;
    const bf16* a0 = A + (long)ra * 1152 + ca;
    const bf16* b0 = B + (long)ra * 2304 + ca;
    const bf16* b1 = B + (long)(128 + ra) * 2304 + ca;
    char* lA  = (char*)As + wave * 1024;
    char* lB0 = (char*)Bs + wave * 1024;
    char* lB1 = (char*)Bs + 8192 + wave * 1024;

    f32x4 acc[4][4] = {};
#pragma unroll 1
    for (int k = 0; k < 36; ++k) {
        __syncthreads();
        async_copy16(a0, lA);
        async_copy16(b0, lB0);
        async_copy16(b1, lB1);
        a0 += 32; b0 += 32; b1 += 32;
        __syncthreads();
        bf16x8 af[4], bfv[4];
#pragma unroll
        for (int t = 0; t < 4; ++t) {
            af[t]  = *(const bf16x8*)(As + (wM + t * 16 + l16) * 32 + quad * 8);
            bfv[t] = *(const bf16x8*)(Bs + (wN + t * 16 + l16) * 32 + quad * 8);
        }
#pragma unroll
        for (int mt = 0; mt < 4; ++mt)
#pragma unroll
            for (int nt = 0; nt < 4; ++nt)
                acc[mt][nt] = __builtin_amdgcn_mfma_f32_16x16x32_bf16(
                    af[mt], bfv[nt], acc[mt][nt], 0, 0, 0);
    }

    // add m-dependent bias c[m] (part of Q·Km^T)
    float cv[4];
#pragma unroll
    for (int nt = 0; nt < 4; ++nt) cv[nt] = cvec[b * 256 + wN + nt * 16 + l16];
#pragma unroll
    for (int mt = 0; mt < 4; ++mt)
#pragma unroll
        for (int nt = 0; nt < 4; ++nt)
#pragma unroll
            for (int r = 0; r < 4; ++r) acc[mt][nt][r] += cv[nt];

    const float scale = 0.029462782549439484f;  // 1/sqrt(1152)

#pragma unroll
    for (int mt = 0; mt < 4; ++mt)
#pragma unroll
        for (int r = 0; r < 4; ++r) {
            float pm = fmaxf(fmaxf(acc[mt][0][r], acc[mt][1][r]),
                             fmaxf(acc[mt][2][r], acc[mt][3][r]));
#pragma unroll
            for (int off = 1; off <= 8; off <<= 1) pm = fmaxf(pm, __shfl_xor(pm, off));
            if (l16 == 0) red[wM + mt * 16 + quad * 4 + r][wc] = pm;
        }
    __syncthreads();
#pragma unroll
    for (int mt = 0; mt < 4; ++mt)
#pragma unroll
        for (int r = 0; r < 4; ++r) {
            const int R = wM + mt * 16 + quad * 4 + r;
            float4 q = *(const float4*)red[R];
            float m = fmaxf(fmaxf(q.x, q.y), fmaxf(q.z, q.w));
            float ps = 0.0f;
#pragma unroll
            for (int nt = 0; nt < 4; ++nt) {
                float e = __expf((acc[mt][nt][r] - m) * scale);
                acc[mt][nt][r] = e;
                ps += e;
            }
#pragma unroll
            for (int off = 1; off <= 8; off <<= 1) ps += __shfl_xor(ps, off);
            if (l16 == 0) red2[R][wc] = ps;
        }
    __syncthreads();
#pragma unroll
    for (int mt = 0; mt < 4; ++mt)
#pragma unroll
        for (int r = 0; r < 4; ++r) {
            const int R = wM + mt * 16 + quad * 4 + r;
            float4 q = *(const float4*)red2[R];
            float inv = 1.0f / (q.x + q.y + q.z + q.w);
            const long gr = b * 1024 + (long)bx * 128 + R;
#pragma unroll
            for (int nt = 0; nt < 4; ++nt)
                P[gr * 256 + wN + nt * 16 + l16] = (bf16)(acc[mt][nt][r] * inv);
        }
}

// Transpose+cvt fp32->bf16: z=0 Wq->slot0, z=1 Wk->slot2, z=2 Wv->slot3 of WT4.
__global__ void cvt_wT_k(const float* __restrict__ Wq, const float* __restrict__ Wk,
                         const float* __restrict__ Wv, bf16* __restrict__ dst) {
    __shared__ bf16 t[64][66];
    const int z = blockIdx.z;
    const float* src = z == 0 ? Wq : z == 1 ? Wk : Wv;
    bf16* d = dst + (long)(z == 0 ? 0 : z == 1 ? 2 : 3) * 1327104;
    const int r0 = blockIdx.y * 64, c0 = blockIdx.x * 64;
    const int tid = threadIdx.x;
    {
        int row = tid >> 4;
        int col4 = (tid & 15) * 4;
#pragma unroll
        for (int p = 0; p < 4; ++p) {
            int r = row + p * 16;
            float4 v = *(const float4*)(src + (long)(r0 + r) * 1152 + c0 + col4);
            t[col4 + 0][r] = (bf16)v.x;
            t[col4 + 1][r] = (bf16)v.y;
            t[col4 + 2][r] = (bf16)v.z;
            t[col4 + 3][r] = (bf16)v.w;
        }
    }
    __syncthreads();
    {
        int orow = tid >> 2;
        int oc = (tid & 3) * 16;
        bf16x8 a, b2;
#pragma unroll
        for (int j = 0; j < 8; ++j) { a[j] = t[orow][oc + j]; b2[j] = t[orow][oc + 8 + j]; }
        bf16* o = d + (long)(c0 + orow) * 1152 + r0 + oc;
        *(bf16x8*)o = a;
        *(bf16x8*)(o + 8) = b2;
    }
}

// Plain cvt Wo -> WT4 slot 1
__global__ void cvt_w_plain_k(const float* __restrict__ Wo, bf16* __restrict__ dst) {
    int i = blockIdx.x * 256 + threadIdx.x;  // 331776 exact
    float4 v = ((const float4*)Wo)[i];
    bf16x4 o = {(bf16)v.x, (bf16)v.y, (bf16)v.z, (bf16)v.w};
    ((bf16x4*)(dst + 1327104))[i] = o;
}

// x fp32 [32768 x 1152] -> xb bf16 (all rows) + xm bf16 (mean over 4-row windows)
__global__ void cvt_merge_x_k(const float* __restrict__ x, bf16* __restrict__ xb,
                              bf16* __restrict__ xm) {
    int i = blockIdx.x * 256 + threadIdx.x;  // 8192*288 exact
    int w = i / 288;
    int c4 = i - w * 288;
    const float4* p = (const float4*)(x + (long)w * 4608) + c4;
    float4 a = p[0], b = p[288], c = p[576], d = p[864];
    bf16x4 oa = {(bf16)a.x, (bf16)a.y, (bf16)a.z, (bf16)a.w};
    bf16x4 ob = {(bf16)b.x, (bf16)b.y, (bf16)b.z, (bf16)b.w};
    bf16x4 oc = {(bf16)c.x, (bf16)c.y, (bf16)c.z, (bf16)c.w};
    bf16x4 od = {(bf16)d.x, (bf16)d.y, (bf16)d.z, (bf16)d.w};
    bf16* base = xb + (long)w * 4608 + c4 * 4;
    *(bf16x4*)(base)        = oa;
    *(bf16x4*)(base + 1152) = ob;
    *(bf16x4*)(base + 2304) = oc;
    *(bf16x4*)(base + 3456) = od;
    float4 s;
    s.x = (a.x + b.x + c.x + d.x) * 0.25f;
    s.y = (a.y + b.y + c.y + d.y) * 0.25f;
    s.z = (a.z + b.z + c.z + d.z) * 0.25f;
    s.w = (a.w + b.w + c.w + d.w) * 0.25f;
    bf16x4 o = {(bf16)s.x, (bf16)s.y, (bf16)s.z, (bf16)s.w};
    *(bf16x4*)(xm + (long)w * 1152 + c4 * 4) = o;
}

// out[row] = dot(M[row,0:1152], v); optionally zero z[row]. One wave per row.
__global__ void rowdot_k(const bf16* __restrict__ M, const float* __restrict__ v,
                         float* __restrict__ out, float* __restrict__ z) {
    const int row = blockIdx.x * 4 + (threadIdx.x >> 6);
    const int lane = threadIdx.x & 63;
    const bf16* mr = M + (long)row * 1152;
    float acc = 0.0f;
#pragma unroll
    for (int j = 0; j < 18; ++j)
        acc += (float)mr[j * 64 + lane] * v[j * 64 + lane];
#pragma unroll
    for (int off = 32; off; off >>= 1) acc += __shfl_xor(acc, off, 64);
    if (lane == 0) {
        out[row] = acc;
        if (z) z[row] = 0.0f;
    }
}

// VW part of UVW [b*256+m][2304]@+1152 -> VWT:[b][1152][256]
__global__ void transpose_vm_k(const bf16* __restrict__ UVW, bf16* __restrict__ VT) {
    __shared__ bf16 t[64][65];
    const int tid = threadIdx.x;
    const int b = blockIdx.z;
    const int d0 = blockIdx.x * 64, m0 = blockIdx.y * 64;
#pragma unroll
    for (int p = 0; p < 2; ++p) {
        int r = (tid >> 3) + p * 32;
        int c = (tid & 7) * 8;
        bf16x8 v = *(const bf16x8*)(UVW + (long)(b * 256 + m0 + r) * 2304 + 1152 + d0 + c);
#pragma unroll
        for (int j = 0; j < 8; ++j) t[c + j][r] = v[j];
    }
    __syncthreads();
#pragma unroll
    for (int p = 0; p < 2; ++p) {
        int r = (tid >> 3) + p * 32;
        int c = (tid & 7) * 8;
        bf16x8 o;
#pragma unroll
        for (int j = 0; j < 8; ++j) o[j] = t[r][c + j];
        *(bf16x8*)(VT + (long)b * 294912 + (long)(d0 + r) * 256 + m0 + c) = o;
    }
}

extern "C" void kernel_launch(void* const* d_in, const int* in_sizes, int n_in,
                              void* d_out, int out_size, void* d_ws, size_t ws_size,
                              hipStream_t stream) {
    const float* x  = (const float*)d_in[0];
    const float* Wq = (const float*)d_in[1];
    const float* bq = (const float*)d_in[2];
    const float* Wk = (const float*)d_in[3];
    const float* bk = (const float*)d_in[4];  (void)bk;  // softmax-invariant
    const float* Wv = (const float*)d_in[5];
    const float* bv = (const float*)d_in[6];
    const float* Wo = (const float*)d_in[7];
    const float* bo = (const float*)d_in[8];
    float* out = (float*)d_out;
    char* ws = (char*)d_ws;

    // ws layout (~108 MB)
    bf16* WT4    = (bf16*)(ws);                  // [WqT | Wo | WkT | WvT], 10,616,832 B
    bf16* WkT_b  = WT4 + 2 * 1327104;
    bf16* Wo_b   = WT4 + 1 * 1327104;
    bf16* WQK2   = (bf16*)(ws + 10616832);       // [Wqk ; Wvo] [2304x1152], 5,308,416 B
    float* biasUV = (float*)(ws + 15925248);     // [2304] = [0 | Wo·bv]
    float* vk     = (float*)(ws + 15934464);     // [1152] = Wk^T·bq
    float* cvec   = (float*)(ws + 15939072);     // [8192] = x_m·vk
    bf16* xm_b   = (bf16*)(ws + 15971840);       // [8192x1152], 18,874,368 B
    bf16* UVW    = (bf16*)(ws + 34846208);       // [8192x2304], 37,748,736 B
    bf16* VWT    = (bf16*)(ws + 72594944);       // [32][1152][256], 18,874,368 B
    bf16* P_b    = (bf16*)(ws + 91469312);       // [32768x256], 16,777,216 B

    // d_out (151 MB fp32) as scratch for x_b; dead before final GEMM writes out.
    bf16* x_b = (bf16*)d_out;                    // 75,497,472 B

    // 1. weight prep: WqT, WkT, WvT (transposed) + Wo (plain), all bf16
    cvt_wT_k<<<dim3(18, 18, 3), 256, 0, stream>>>(Wq, Wk, Wv, WT4);
    cvt_w_plain_k<<<1296, 256, 0, stream>>>(Wo, WT4);
    cvt_merge_x_k<<<9216, 256, 0, stream>>>(x, x_b, xm_b);

    // 2. Wqk = WqT·WkT^T = Wq^T·Wk (z=0); Wvo = Wo·WvT^T = Wo·Wv (z=1)
    gemm_bt<bf16, false><<<dim3(9, 9, 2), 256, 0, stream>>>(
        WT4, WT4 + 2 * 1327104, nullptr, WQK2,
        1152, 1152, 1152, 1152, 1152, 1.0f, 1327104, 1327104, 1327104);

    // 3. small vectors: vk = WkT·bq (also zero biasUV[0:1152]); biasUV[1152:] = Wo·bv
    rowdot_k<<<288, 256, 0, stream>>>(WkT_b, bq, vk, biasUV);
    rowdot_k<<<288, 256, 0, stream>>>(Wo_b, bv, biasUV + 1152, nullptr);

    // 4. [U | VW] = x_m @ WQK2^T + biasUV
    gemm_bt<bf16, true><<<dim3(18, 64, 1), 256, 0, stream>>>(
        xm_b, WQK2, biasUV, UVW, 2304, 1152, 1152, 1152, 2304, 1.0f, 0, 0, 0);

    // 5. c[m] = x_m · vk
    rowdot_k<<<2048, 256, 0, stream>>>(xm_b, vk, cvec, nullptr);

    // 6. VWT = transpose(VW) per batch
    transpose_vm_k<<<dim3(18, 4, 32), 256, 0, stream>>>(UVW, VWT);

    // 7. P = softmax((x@U^T + c)/sqrt(D))
    scores_softmax_k<<<dim3(8, 32), 512, 0, stream>>>(x_b, UVW, cvec, P_b);

    // 8. out = P @ VWT^T + bo (fp32)
    gemm_bt<float, true><<<dim3(9, 8, 32), 256, 0, stream>>>(
        P_b, VWT, bo, out, 1152, 256, 256, 256, 1152, 1.0f,
        1024L * 256, 1152L * 256, 1024L * 1152);
}